// Round 4
// baseline (382.937 us; speedup 1.0000x reference)
//
#include <hip/hip_runtime.h>
#include <hip/hip_bf16.h>

#define D      128
#define LG     9
#define CHUNK  512   // (1 << LG)

typedef __attribute__((ext_vector_type(8))) short          short8;
typedef __attribute__((ext_vector_type(8))) unsigned short ushort8;
typedef __attribute__((ext_vector_type(4))) float          floatx4;

__device__ inline float b2f(unsigned short u) {
    return __uint_as_float(((unsigned)u) << 16);
}
__device__ inline short f2bf(float f) {
    __hip_bfloat16 h = __float2bfloat16(f);
    unsigned short u;
    __builtin_memcpy(&u, &h, 2);
    return (short)u;
}

__global__ void init_out_kernel(float* out, int out_size) {
    int t = threadIdx.x;
    if (t < out_size) out[t] = -INFINITY;
}

// Pass 1: single gather pass. Chunk-LOCAL inclusive cumsum of embedding rows,
// stored bf16; chunk totals to sumE (fp32).
__global__ void local_scan_kernel(const int* __restrict__ tokens,
                                  const float* __restrict__ emb,
                                  unsigned short* __restrict__ S,
                                  float* __restrict__ sumE, int n) {
    __shared__ int toks[CHUNK];
    int c  = blockIdx.x;
    int i0 = c << LG;
    int cnt = min(CHUNK, n - i0);
    for (int t = threadIdx.x; t < cnt; t += 128) toks[t] = tokens[i0 + t];
    __syncthreads();
    int d = threadIdx.x;
    float run = 0.f;
    #pragma unroll 8
    for (int j = 0; j < cnt; ++j) {
        run += emb[(size_t)toks[j] * D + d];
        S[(size_t)(i0 + j) * D + d] = (unsigned short)f2bf(run);
    }
    sumE[(size_t)c * D + d] = run;
}

// Pass 2: in-place exclusive scan of chunk totals (one wave per dim).
__global__ void scan_kernel(float* sumE, int C) {
    int d    = blockIdx.x;     // 0..127
    int lane = threadIdx.x;    // 0..63
    float carry = 0.f;
    for (int c0 = 0; c0 < C; c0 += 64) {
        int c = c0 + lane;
        float v = (c < C) ? sumE[(size_t)c * D + d] : 0.f;
        float incl = v;
        #pragma unroll
        for (int off = 1; off < 64; off <<= 1) {
            float t = __shfl_up(incl, off);
            if (lane >= off) incl += t;
        }
        if (c < C) sumE[(size_t)c * D + d] = carry + incl - v;  // exclusive
        carry += __shfl(incl, 63);
    }
}

__device__ inline void atomicMaxF(float* addr, float v) {
    if (v >= 0.f) atomicMax((int*)addr, __float_as_int(v));
    else          atomicMin((unsigned int*)addr, __float_as_uint(v));
}

// Pass 3: h = W*(S[end]-S[prev]) + cnt*b via MFMA; out = per-dim max.
// W^T staged per-block in LDS as bf16 fragments; read via ds_read_b128.
__global__ __launch_bounds__(256, 4) void max_pass_kernel(
        const int* __restrict__ ends, const unsigned short* __restrict__ S,
        const float* __restrict__ prefE, const float* __restrict__ W,
        const float* __restrict__ bvec, float* __restrict__ out,
        int n, int n_tiles, int tpw) {
    // Wlds[t*256 + kk*64 + c*4 + kg][j] = bf16(W[(t*16+c)*128 + kk*32 + kg*8 + j])
    __shared__ short8 Wlds[2048];             // 32 KB
    __shared__ float  red[4][8][16];
    int tid = threadIdx.x;

    // Cooperative W stage: 2048 fragments / 256 threads = 8 each.
    for (int e = tid; e < 2048; e += 256) {
        int t  = e >> 8;
        int kk = (e >> 6) & 3;
        int cc = (e >> 2) & 15;
        int kg = e & 3;
        const float* src = W + (size_t)(t * 16 + cc) * D + kk * 32 + kg * 8;
        floatx4 f0 = *(const floatx4*)src;
        floatx4 f1 = *(const floatx4*)(src + 4);
        short8 w;
        #pragma unroll
        for (int j = 0; j < 4; ++j) { w[j] = f2bf(f0[j]); w[j + 4] = f2bf(f1[j]); }
        Wlds[e] = w;
    }
    __syncthreads();

    int lane = tid & 63;
    int wid  = tid >> 6;
    int c  = lane & 15;   // node-in-tile / C-col index
    int kg = lane >> 4;   // k-subgroup 0..3
    int wbase = c * 4 + kg;

    float bc[8];
    #pragma unroll
    for (int t = 0; t < 8; ++t) bc[t] = bvec[t * 16 + c];
    float mx[8];
    #pragma unroll
    for (int t = 0; t < 8; ++t) mx[t] = -INFINITY;

    int gw = blockIdx.x * 4 + wid;
    int t0 = gw * tpw;
    int t1 = min(n_tiles, t0 + tpw);
    if (t0 < t1) {
        int e_cur = ends[min(t0 * 16 + c, n - 1)];
        for (int tt = t0; tt < t1; ++tt) {
            int base = tt * 16;
            int node = base + c;
            bool vr  = node < n;
            int e = e_cur;
            // prefetch next tile's ends (latency hides under S loads)
            int nidx = (tt + 1 < t1) ? (tt + 1) * 16 + c : node;
            int e_next = ends[min(nidx, n - 1)];
            int p  = node - 1;
            int pc = max(p, 0);
            int ce = e >> LG, cp = pc >> LG;
            bool fast = __all(vr && p >= 0 && ce == cp);
            const ushort8* pe = (const ushort8*)(S + (size_t)e  * D) + kg;
            const ushort8* pp = (const ushort8*)(S + (size_t)pc * D) + kg;
            short8 A[4];
            if (fast) {
                #pragma unroll
                for (int kk = 0; kk < 4; ++kk) {
                    ushort8 se = pe[kk * 4];
                    ushort8 sp = pp[kk * 4];
                    short8 a;
                    #pragma unroll
                    for (int j = 0; j < 8; ++j)
                        a[j] = f2bf(b2f(se[j]) - b2f(sp[j]));
                    A[kk] = a;
                }
            } else {
                const float* qe = prefE + (size_t)ce * D + kg * 8;
                const float* qp = prefE + (size_t)cp * D + kg * 8;
                float vmask = vr ? 1.f : 0.f;
                float pmask = (p >= 0) ? 1.f : 0.f;
                #pragma unroll
                for (int kk = 0; kk < 4; ++kk) {
                    ushort8 se = pe[kk * 4];
                    ushort8 sp = pp[kk * 4];
                    floatx4 qe0 = *(const floatx4*)(qe + kk * 32);
                    floatx4 qe1 = *(const floatx4*)(qe + kk * 32 + 4);
                    floatx4 qp0 = *(const floatx4*)(qp + kk * 32);
                    floatx4 qp1 = *(const floatx4*)(qp + kk * 32 + 4);
                    short8 a;
                    #pragma unroll
                    for (int j = 0; j < 4; ++j) {
                        float fe0 = b2f(se[j])     + qe0[j];
                        float fp0 = b2f(sp[j])     + qp0[j];
                        float fe1 = b2f(se[j + 4]) + qe1[j];
                        float fp1 = b2f(sp[j + 4]) + qp1[j];
                        a[j]     = f2bf(vmask * (fe0 - pmask * fp0));
                        a[j + 4] = f2bf(vmask * (fe1 - pmask * fp1));
                    }
                    A[kk] = a;
                }
            }
            floatx4 cnt;
            #pragma unroll
            for (int i = 0; i < 4; ++i) {
                int nd = base + kg * 4 + i;
                float ee = (float)__shfl(e, kg * 4 + i);
                cnt[i] = (nd < n) ? (ee - (float)nd + 1.f) : 0.f;
            }
            #pragma unroll
            for (int t = 0; t < 8; ++t) {
                floatx4 acc = {0.f, 0.f, 0.f, 0.f};
                #pragma unroll
                for (int kk = 0; kk < 4; ++kk) {
                    short8 wf = Wlds[t * 256 + kk * 64 + wbase];
                    acc = __builtin_amdgcn_mfma_f32_16x16x32_bf16(A[kk], wf, acc, 0, 0, 0);
                }
                #pragma unroll
                for (int i = 0; i < 4; ++i) {
                    int nd = base + kg * 4 + i;
                    float h = acc[i] + cnt[i] * bc[t];
                    if (nd < n) mx[t] = fmaxf(mx[t], h);
                }
            }
            e_cur = e_next;
        }
    }
    // Reduce across the 4 k-subgroups (they hold the same d = t*16+c).
    #pragma unroll
    for (int t = 0; t < 8; ++t) {
        float v = mx[t];
        v = fmaxf(v, __shfl_xor(v, 16));
        v = fmaxf(v, __shfl_xor(v, 32));
        mx[t] = v;
    }
    if (kg == 0) {
        #pragma unroll
        for (int t = 0; t < 8; ++t) red[wid][t][c] = mx[t];
    }
    __syncthreads();
    if (tid < 128) {
        int t = tid >> 4, cc = tid & 15;
        float v = fmaxf(fmaxf(red[0][t][cc], red[1][t][cc]),
                        fmaxf(red[2][t][cc], red[3][t][cc]));
        atomicMaxF(&out[t * 16 + cc], v);
    }
}

extern "C" void kernel_launch(void* const* d_in, const int* in_sizes, int n_in,
                              void* d_out, int out_size, void* d_ws, size_t ws_size,
                              hipStream_t stream) {
    const int*   tokens = (const int*)d_in[0];
    const int*   ends   = (const int*)d_in[1];
    const float* emb    = (const float*)d_in[2];
    const float* W      = (const float*)d_in[3];
    const float* bvec   = (const float*)d_in[4];
    float* out = (float*)d_out;
    int n = in_sizes[0];
    int C = (n + CHUNK - 1) >> LG;

    unsigned short* S    = (unsigned short*)d_ws;          // n*128 bf16 = 256 MB
    float*          sumE = (float*)(S + (size_t)n * D);    // C*128 fp32 (scanned in place)
    // total = n*256 + C*512 bytes = 257,000,448 for n=1e6 (same proven footprint)

    init_out_kernel<<<1, 128, 0, stream>>>(out, out_size);
    local_scan_kernel<<<C, 128, 0, stream>>>(tokens, emb, S, sumE, n);
    scan_kernel<<<128, 64, 0, stream>>>(sumE, C);

    int n_tiles = (n + 15) / 16;
    int nblocks = 1024;                           // 4 blocks/CU (LDS-capped)
    int gw_cnt  = nblocks * 4;
    int tpw = (n_tiles + gw_cnt - 1) / gw_cnt;    // 16 tiles per wave
    max_pass_kernel<<<nblocks, 256, 0, stream>>>(ends, S, sumE, W, bvec, out,
                                                 n, n_tiles, tpw);
}

// Round 5
// 310.804 us; speedup vs baseline: 1.2321x; 1.2321x over previous
//
#include <hip/hip_runtime.h>
#include <hip/hip_bf16.h>

#define D      128
#define LG     9
#define CHUNK  512   // (1 << LG)

typedef __attribute__((ext_vector_type(8))) short          short8;
typedef __attribute__((ext_vector_type(8))) unsigned short ushort8;
typedef __attribute__((ext_vector_type(4))) float          floatx4;

__device__ inline float b2f(unsigned short u) {
    return __uint_as_float(((unsigned)u) << 16);
}
__device__ inline short f2bf(float f) {
    __hip_bfloat16 h = __float2bfloat16(f);
    unsigned short u;
    __builtin_memcpy(&u, &h, 2);
    return (short)u;
}

__global__ void init_out_kernel(float* out, int out_size) {
    int t = threadIdx.x;
    if (t < out_size) out[t] = -INFINITY;
}

// Pass 1: single gather pass. Chunk-LOCAL inclusive cumsum of embedding rows,
// stored bf16; chunk totals to sumE (fp32).
__global__ void local_scan_kernel(const int* __restrict__ tokens,
                                  const float* __restrict__ emb,
                                  unsigned short* __restrict__ S,
                                  float* __restrict__ sumE, int n) {
    __shared__ int toks[CHUNK];
    int c  = blockIdx.x;
    int i0 = c << LG;
    int cnt = min(CHUNK, n - i0);
    for (int t = threadIdx.x; t < cnt; t += 128) toks[t] = tokens[i0 + t];
    __syncthreads();
    int d = threadIdx.x;
    float run = 0.f;
    #pragma unroll 8
    for (int j = 0; j < cnt; ++j) {
        run += emb[(size_t)toks[j] * D + d];
        S[(size_t)(i0 + j) * D + d] = (unsigned short)f2bf(run);
    }
    sumE[(size_t)c * D + d] = run;
}

// Pass 2: in-place exclusive scan of chunk totals (one wave per dim).
__global__ void scan_kernel(float* sumE, int C) {
    int d    = blockIdx.x;     // 0..127
    int lane = threadIdx.x;    // 0..63
    float carry = 0.f;
    for (int c0 = 0; c0 < C; c0 += 64) {
        int c = c0 + lane;
        float v = (c < C) ? sumE[(size_t)c * D + d] : 0.f;
        float incl = v;
        #pragma unroll
        for (int off = 1; off < 64; off <<= 1) {
            float t = __shfl_up(incl, off);
            if (lane >= off) incl += t;
        }
        if (c < C) sumE[(size_t)c * D + d] = carry + incl - v;  // exclusive
        carry += __shfl(incl, 63);
    }
}

__device__ inline void atomicMaxF(float* addr, float v) {
    if (v >= 0.f) atomicMax((int*)addr, __float_as_int(v));
    else          atomicMin((unsigned int*)addr, __float_as_uint(v));
}

// Pass 3: h = W*(S[end]-S[prev]) + cnt*b via MFMA; out = per-dim max.
// Wave-PAIR scheme: two waves share each node tile; each wave holds HALF of
// W^T (4 of 8 output-tiles) in registers (64 VGPR). S reads duplicated within
// the pair dedupe in L1/L2 (same CU). 1024 streams total (vs 4096 in R4).
__global__ __launch_bounds__(256, 2) void max_pass_kernel(
        const int* __restrict__ ends, const unsigned short* __restrict__ S,
        const float* __restrict__ prefE, const float* __restrict__ W,
        const float* __restrict__ bvec, float* __restrict__ out,
        int n, int n_tiles, int tpp) {
    __shared__ float red[4][4][16];   // [wid][tl][c]
    int tid  = threadIdx.x;
    int lane = tid & 63;
    int wid  = tid >> 6;
    int c  = lane & 15;   // node-in-tile / C-col index
    int kg = lane >> 4;   // k-subgroup 0..3
    int tw   = wid & 1;   // which half of the 8 output-tiles
    int pair = blockIdx.x * 2 + (wid >> 1);

    // Preload this wave's half of W (bf16 fragments) and bias slice.
    short8 Wf[4][4];
    float  bc[4];
    #pragma unroll
    for (int tl = 0; tl < 4; ++tl) {
        int tg = tw * 4 + tl;
        const float* wr = W + (size_t)(tg * 16 + c) * D + kg * 8;
        bc[tl] = bvec[tg * 16 + c];
        #pragma unroll
        for (int kk = 0; kk < 4; ++kk) {
            floatx4 f0 = *(const floatx4*)(wr + kk * 32);
            floatx4 f1 = *(const floatx4*)(wr + kk * 32 + 4);
            short8 w;
            #pragma unroll
            for (int j = 0; j < 4; ++j) { w[j] = f2bf(f0[j]); w[j + 4] = f2bf(f1[j]); }
            Wf[tl][kk] = w;
        }
    }
    float mx[4];
    #pragma unroll
    for (int tl = 0; tl < 4; ++tl) mx[tl] = -INFINITY;

    int t0 = pair * tpp;
    int t1 = min(n_tiles, t0 + tpp);
    if (t0 < t1) {
        int e_cur = ends[min(t0 * 16 + c, n - 1)];
        for (int tt = t0; tt < t1; ++tt) {
            int base = tt * 16;
            int node = base + c;
            bool vr  = node < n;
            int e = e_cur;
            // prefetch next tile's ends (latency hides under S loads)
            int nidx = (tt + 1 < t1) ? (tt + 1) * 16 + c : node;
            int e_next = ends[min(nidx, n - 1)];
            int p  = node - 1;
            int pc = max(p, 0);
            int ce = e >> LG, cp = pc >> LG;
            bool fast = __all(vr && p >= 0 && ce == cp);
            const ushort8* pe = (const ushort8*)(S + (size_t)e  * D) + kg;
            const ushort8* pp = (const ushort8*)(S + (size_t)pc * D) + kg;
            short8 A[4];
            if (fast) {
                #pragma unroll
                for (int kk = 0; kk < 4; ++kk) {
                    ushort8 se = pe[kk * 4];
                    ushort8 sp = pp[kk * 4];
                    short8 a;
                    #pragma unroll
                    for (int j = 0; j < 8; ++j)
                        a[j] = f2bf(b2f(se[j]) - b2f(sp[j]));
                    A[kk] = a;
                }
            } else {
                const float* qe = prefE + (size_t)ce * D + kg * 8;
                const float* qp = prefE + (size_t)cp * D + kg * 8;
                float vmask = vr ? 1.f : 0.f;
                float pmask = (p >= 0) ? 1.f : 0.f;
                #pragma unroll
                for (int kk = 0; kk < 4; ++kk) {
                    ushort8 se = pe[kk * 4];
                    ushort8 sp = pp[kk * 4];
                    floatx4 qe0 = *(const floatx4*)(qe + kk * 32);
                    floatx4 qe1 = *(const floatx4*)(qe + kk * 32 + 4);
                    floatx4 qp0 = *(const floatx4*)(qp + kk * 32);
                    floatx4 qp1 = *(const floatx4*)(qp + kk * 32 + 4);
                    short8 a;
                    #pragma unroll
                    for (int j = 0; j < 4; ++j) {
                        float fe0 = b2f(se[j])     + qe0[j];
                        float fp0 = b2f(sp[j])     + qp0[j];
                        float fe1 = b2f(se[j + 4]) + qe1[j];
                        float fp1 = b2f(sp[j + 4]) + qp1[j];
                        a[j]     = f2bf(vmask * (fe0 - pmask * fp0));
                        a[j + 4] = f2bf(vmask * (fe1 - pmask * fp1));
                    }
                    A[kk] = a;
                }
            }
            floatx4 cnt;
            #pragma unroll
            for (int i = 0; i < 4; ++i) {
                int nd = base + kg * 4 + i;
                float ee = (float)__shfl(e, kg * 4 + i);
                cnt[i] = (nd < n) ? (ee - (float)nd + 1.f) : 0.f;
            }
            #pragma unroll
            for (int tl = 0; tl < 4; ++tl) {
                floatx4 acc = {0.f, 0.f, 0.f, 0.f};
                acc = __builtin_amdgcn_mfma_f32_16x16x32_bf16(A[0], Wf[tl][0], acc, 0, 0, 0);
                acc = __builtin_amdgcn_mfma_f32_16x16x32_bf16(A[1], Wf[tl][1], acc, 0, 0, 0);
                acc = __builtin_amdgcn_mfma_f32_16x16x32_bf16(A[2], Wf[tl][2], acc, 0, 0, 0);
                acc = __builtin_amdgcn_mfma_f32_16x16x32_bf16(A[3], Wf[tl][3], acc, 0, 0, 0);
                #pragma unroll
                for (int i = 0; i < 4; ++i) {
                    int nd = base + kg * 4 + i;
                    float h = acc[i] + cnt[i] * bc[tl];
                    if (nd < n) mx[tl] = fmaxf(mx[tl], h);
                }
            }
            e_cur = e_next;
        }
    }
    // Reduce across the 4 k-subgroups (they hold the same d = tg*16+c).
    #pragma unroll
    for (int tl = 0; tl < 4; ++tl) {
        float v = mx[tl];
        v = fmaxf(v, __shfl_xor(v, 16));
        v = fmaxf(v, __shfl_xor(v, 32));
        mx[tl] = v;
    }
    if (kg == 0) {
        #pragma unroll
        for (int tl = 0; tl < 4; ++tl) red[wid][tl][c] = mx[tl];
    }
    __syncthreads();
    if (tid < 128) {
        // tid = tw*64 + tl*16 + cc
        int twf = tid >> 6;
        int tl  = (tid >> 4) & 3;
        int cc  = tid & 15;
        float v = fmaxf(red[twf][tl][cc], red[twf + 2][tl][cc]);
        atomicMaxF(&out[(twf * 4 + tl) * 16 + cc], v);
    }
}

extern "C" void kernel_launch(void* const* d_in, const int* in_sizes, int n_in,
                              void* d_out, int out_size, void* d_ws, size_t ws_size,
                              hipStream_t stream) {
    const int*   tokens = (const int*)d_in[0];
    const int*   ends   = (const int*)d_in[1];
    const float* emb    = (const float*)d_in[2];
    const float* W      = (const float*)d_in[3];
    const float* bvec   = (const float*)d_in[4];
    float* out = (float*)d_out;
    int n = in_sizes[0];
    int C = (n + CHUNK - 1) >> LG;

    unsigned short* S    = (unsigned short*)d_ws;          // n*128 bf16 = 256 MB
    float*          sumE = (float*)(S + (size_t)n * D);    // C*128 fp32 (scanned in place)
    // total = n*256 + C*512 bytes = 257,000,448 for n=1e6 (same proven footprint)

    init_out_kernel<<<1, 128, 0, stream>>>(out, out_size);
    local_scan_kernel<<<C, 128, 0, stream>>>(tokens, emb, S, sumE, n);
    scan_kernel<<<128, 64, 0, stream>>>(sumE, C);

    int n_tiles = (n + 15) / 16;
    int nblocks = 512;                            // 2 blocks/CU; 1024 wave-pairs
    int pairs   = nblocks * 2;
    int tpp = (n_tiles + pairs - 1) / pairs;      // ~62 tiles per pair
    max_pass_kernel<<<nblocks, 256, 0, stream>>>(ends, S, sumE, W, bvec, out,
                                                 n, n_tiles, tpp);
}